// Round 4
// baseline (1868.039 us; speedup 1.0000x reference)
//
#include <hip/hip_runtime.h>
#include <hip/hip_bf16.h>

// MeshConvNet on MI355X (gfx950) — round 4: kill the vmcnt(0) barrier drain.
// __syncthreads() in the K-loop emits s_waitcnt vmcnt(0) before s_barrier, which
// drains the prefetched gather loads every chunk (full L3/HBM latency exposed at
// every barrier). Replace with LDS-scoped fences + s_barrier => lgkmcnt(0) only;
// register-destined prefetch loads stay in flight across the barrier and complete
// under the MFMA phase. Numerics unchanged (3-product split-bf16, fp32 h).

#define B_ 4
#define E_ 16384

typedef short short8 __attribute__((ext_vector_type(8)));
typedef float floatx4 __attribute__((ext_vector_type(4)));

__device__ __forceinline__ float lk(float v) { return v > 0.0f ? v : 0.01f * v; }
__device__ __forceinline__ float b2f(__hip_bfloat16 h) { return __bfloat162float(h); }
__device__ __forceinline__ __hip_bfloat16 f2b(float f) { return __float2bfloat16(f); }

// Barrier that only waits on LDS (lgkmcnt), NOT on in-flight global loads (vmcnt).
__device__ __forceinline__ void barrier_lds() {
    __builtin_amdgcn_fence(__ATOMIC_RELEASE, "workgroup", "local");
    __builtin_amdgcn_s_barrier();
    __builtin_amdgcn_fence(__ATOMIC_ACQUIRE, "workgroup", "local");
}

template <typename TS>
struct Cvt;
template <>
struct Cvt<float> {
    static __device__ __forceinline__ float to(float f) { return f; }
    static __device__ __forceinline__ float from(float s) { return s; }
};
template <>
struct Cvt<__hip_bfloat16> {
    static __device__ __forceinline__ __hip_bfloat16 to(float f) { return f2b(f); }
    static __device__ __forceinline__ float from(__hip_bfloat16 s) { return b2f(s); }
};

// ---------------- x [B][128][E] fp32 -> xT [B*E][128] TS ----------------
template <typename TS>
__global__ void k_transpose_x(const float* __restrict__ x, TS* __restrict__ xT) {
    __shared__ float t[32][33];
    const int b = blockIdx.z, c0 = blockIdx.y * 32, e0 = blockIdx.x * 32;
    const int tx = threadIdx.x & 31, ty = threadIdx.x >> 5;
#pragma unroll
    for (int i = 0; i < 4; ++i) {
        const int c = ty + i * 8;
        t[c][tx] = x[((size_t)b * 128 + c0 + c) * E_ + e0 + tx];
    }
    __syncthreads();
#pragma unroll
    for (int i = 0; i < 4; ++i) {
        const int e = ty + i * 8;
        xT[((size_t)b * E_ + e0 + e) * 128 + c0 + tx] = Cvt<TS>::to(t[tx][e]);
    }
}

// ---- W [256][C][7] fp32 -> hi/lo bf16 [256][C*8] (k=c*8+f, f=7 -> 0) ----
__global__ void k_prep_w(const float* __restrict__ w, __hip_bfloat16* __restrict__ wh,
                         __hip_bfloat16* __restrict__ wl, int C) {
    const int idx = blockIdx.x * blockDim.x + threadIdx.x;  // o*C + c
    if (idx >= 256 * C) return;
    const float* src = w + (size_t)idx * 7;
    __hip_bfloat16* dh = wh + (size_t)idx * 8;
    __hip_bfloat16* dl = wl + (size_t)idx * 8;
#pragma unroll
    for (int f = 0; f < 7; ++f) {
        const float v = src[f];
        const __hip_bfloat16 hi = f2b(v);
        dh[f] = hi;
        dl[f] = f2b(v - b2f(hi));
    }
    dh[7] = f2b(0.0f);
    dl[7] = f2b(0.0f);
}

// ---------------- per-channel sum & sumsq of leaky(h), h [B*E][256] ----------------
template <typename TS>
__global__ void k_bn_stats(const TS* __restrict__ h, float* __restrict__ stats) {
    const int c = threadIdx.x;
    const size_t r0 = (size_t)blockIdx.x * 64;  // 1024 blocks x 64 rows
    float s = 0.0f, q = 0.0f;
    for (int r = 0; r < 64; ++r) {
        const float v = lk(Cvt<TS>::from(h[(r0 + r) * 256 + c]));
        s += v;
        q += v * v;
    }
    atomicAdd(&stats[c], s);
    atomicAdd(&stats[256 + c], q);
}

__global__ void k_bn_finalize(const float* __restrict__ stats, const float* __restrict__ gamma,
                              const float* __restrict__ beta, float* __restrict__ scale,
                              float* __restrict__ bias) {
    const int c = threadIdx.x;
    const float n = 1.0f / 65536.0f;
    const float mean = stats[c] * n;
    const float var = stats[256 + c] * n - mean * mean;
    const float inv = rsqrtf(var + 1e-5f);
    const float s = gamma[c] * inv;
    scale[c] = s;
    bias[c] = beta[c] - mean * s;
}

// ---------------- fused gather + features + split-bf16 MFMA GEMM ----------------
// 512 thr = 8 waves; tile 128 edges x 256 outs; K-chunk = 4 channels (32 k) x {hi,lo}.
// Pipelined: chunk ci+1's gather + B loads in flight through chunk ci's MFMA phase;
// in-loop barriers are LDS-scoped (no vmcnt drain).
template <int C, bool BN, typename TS>
__global__ __launch_bounds__(512, 2) void k_conv(const TS* __restrict__ hin,
                                                 const int* __restrict__ edges,
                                                 const __hip_bfloat16* __restrict__ wh,
                                                 const __hip_bfloat16* __restrict__ wl,
                                                 const float* __restrict__ scale,
                                                 const float* __restrict__ bias,
                                                 TS* __restrict__ hout) {
    constexpr int K = C * 8;
    constexpr int NCH = C / 4;
    constexpr int AS = 72;  // 144 B row stride: 16B-aligned, bank-group uniform mod 8
    __shared__ __align__(16) __hip_bfloat16 Asm[128 * AS];
    __shared__ __align__(16) __hip_bfloat16 Bsm[256 * AS];
    __shared__ float ssc[C];
    __shared__ float ssb[C];

    const int tid = threadIdx.x;
    const int tm = blockIdx.x;  // 512 m-tiles (128 per batch)
    const int b = tm >> 7;
    const int e0 = (tm & 127) * 128;

    if constexpr (BN) {
        if (tid < C) {
            ssc[tid] = scale[tid];
            ssb[tid] = bias[tid];
        }
    }

    // ---- A-gather assignment: 128 edges x 4 channel-threads
    const int e_loc = tid & 127;
    const int c_sub = tid >> 7;  // my channel within the 4-chunk (0..3)
    const int4 nb = *reinterpret_cast<const int4*>(edges + (((size_t)b * E_) + e0 + e_loc) * 4);
    const size_t rb = (size_t)b * E_;
    const TS* rp0 = hin + (rb + e0 + e_loc) * C + c_sub;
    const TS* rp1 = hin + (rb + nb.x) * C + c_sub;
    const TS* rp2 = hin + (rb + nb.y) * C + c_sub;
    const TS* rp3 = hin + (rb + nb.z) * C + c_sub;
    const TS* rp4 = hin + (rb + nb.w) * C + c_sub;

    // ---- B-staging assignment: 256 rows x 2 threads (2 x uint4 per plane each)
    const int brow = tid >> 1;
    const int bq = tid & 1;
    const __hip_bfloat16* whp = wh + (size_t)brow * K + bq * 16;
    const __hip_bfloat16* wlp = wl + (size_t)brow * K + bq * 16;

    floatx4 acc[4][4];
#pragma unroll
    for (int i = 0; i < 4; ++i)
#pragma unroll
        for (int j = 0; j < 4; ++j) {
            floatx4 z = {0.0f, 0.0f, 0.0f, 0.0f};
            acc[i][j] = z;
        }

    const int wave = tid >> 6, lane = tid & 63;
    const int wm = (wave & 1) * 64;   // 0 / 64
    const int wn = (wave >> 1) * 64;  // 0 / 64 / 128 / 192
    const int qd = lane >> 4, l15 = lane & 15;

    // ---- pipeline preload: chunk 0
    float pA0 = Cvt<TS>::from(rp0[0]);
    float pA1 = Cvt<TS>::from(rp1[0]);
    float pA2 = Cvt<TS>::from(rp2[0]);
    float pA3 = Cvt<TS>::from(rp3[0]);
    float pA4 = Cvt<TS>::from(rp4[0]);
    uint4 wBh0 = *reinterpret_cast<const uint4*>(whp);
    uint4 wBh1 = *reinterpret_cast<const uint4*>(whp + 8);
    uint4 wBl0 = *reinterpret_cast<const uint4*>(wlp);
    uint4 wBl1 = *reinterpret_cast<const uint4*>(wlp + 8);

    if constexpr (BN) __syncthreads();  // once, before the loop: ssc/ssb visibility

    for (int ci = 0; ci < NCH; ++ci) {
        // ---- issue next chunk's loads first (maximize load->use distance; no
        //      barrier in this kernel drains vmcnt, so they fly through MFMA phase)
        float nA0, nA1, nA2, nA3, nA4;
        uint4 nBh0, nBh1, nBl0, nBl1;
        if (ci + 1 < NCH) {
            const int co = (ci + 1) * 4;
            nA0 = Cvt<TS>::from(rp0[co]);
            nA1 = Cvt<TS>::from(rp1[co]);
            nA2 = Cvt<TS>::from(rp2[co]);
            nA3 = Cvt<TS>::from(rp3[co]);
            nA4 = Cvt<TS>::from(rp4[co]);
            const int ko = (ci + 1) * 32;
            nBh0 = *reinterpret_cast<const uint4*>(whp + ko);
            nBh1 = *reinterpret_cast<const uint4*>(whp + ko + 8);
            nBl0 = *reinterpret_cast<const uint4*>(wlp + ko);
            nBl1 = *reinterpret_cast<const uint4*>(wlp + ko + 8);
        }

        // ---- stage A: features for my (edge, channel) from prefetched regs
        {
            float f0 = pA0, f1 = pA1, f2 = pA2, f3 = pA3, f4 = pA4;
            if constexpr (BN) {
                const float sA = ssc[ci * 4 + c_sub];
                const float bA = ssb[ci * 4 + c_sub];
                f0 = lk(f0) * sA + bA;
                f1 = lk(f1) * sA + bA;
                f2 = lk(f2) * sA + bA;
                f3 = lk(f3) * sA + bA;
                f4 = lk(f4) * sA + bA;
            }
            float gf[8];
            gf[0] = f0;
            gf[1] = f1 + f3;
            gf[2] = f2 + f4;
            gf[3] = fabsf(f1 - f3);
            gf[4] = fabsf(f2 - f4);
            gf[5] = gf[1] + gf[2];
            const float avg = 0.25f * gf[5];
            const float d1 = f1 - avg, d2 = f2 - avg, d3 = f3 - avg, d4 = f4 - avg;
            gf[6] = d1 * d1 + d2 * d2 + d3 * d3 + d4 * d4;
            gf[7] = 0.0f;
            union U {
                short8 v;
                __hip_bfloat16 h[8];
            } uh, ul;
#pragma unroll
            for (int f = 0; f < 8; ++f) {
                const __hip_bfloat16 hi = f2b(gf[f]);
                uh.h[f] = hi;
                ul.h[f] = f2b(gf[f] - b2f(hi));
            }
            *reinterpret_cast<short8*>(&Asm[e_loc * AS + c_sub * 8]) = uh.v;
            *reinterpret_cast<short8*>(&Asm[e_loc * AS + 32 + c_sub * 8]) = ul.v;
        }
        // ---- stage B from prefetched regs
        *reinterpret_cast<uint4*>(&Bsm[brow * AS + bq * 16]) = wBh0;
        *reinterpret_cast<uint4*>(&Bsm[brow * AS + bq * 16 + 8]) = wBh1;
        *reinterpret_cast<uint4*>(&Bsm[brow * AS + 32 + bq * 16]) = wBl0;
        *reinterpret_cast<uint4*>(&Bsm[brow * AS + 32 + bq * 16 + 8]) = wBl1;

        barrier_lds();  // lgkmcnt(0) + s_barrier: does NOT drain in-flight global loads

        // ---- MFMA: 4x4 tiles x 3-product split
        const int colh = qd * 8, coll = 32 + qd * 8;
        short8 ah[4], al[4], bh[4], bl[4];
#pragma unroll
        for (int mt = 0; mt < 4; ++mt) {
            const int r = (wm + mt * 16 + l15) * AS;
            ah[mt] = *reinterpret_cast<const short8*>(&Asm[r + colh]);
            al[mt] = *reinterpret_cast<const short8*>(&Asm[r + coll]);
        }
#pragma unroll
        for (int nt = 0; nt < 4; ++nt) {
            const int r = (wn + nt * 16 + l15) * AS;
            bh[nt] = *reinterpret_cast<const short8*>(&Bsm[r + colh]);
            bl[nt] = *reinterpret_cast<const short8*>(&Bsm[r + coll]);
        }
#pragma unroll
        for (int mt = 0; mt < 4; ++mt)
#pragma unroll
            for (int nt = 0; nt < 4; ++nt) {
                acc[mt][nt] =
                    __builtin_amdgcn_mfma_f32_16x16x32_bf16(ah[mt], bh[nt], acc[mt][nt], 0, 0, 0);
                acc[mt][nt] =
                    __builtin_amdgcn_mfma_f32_16x16x32_bf16(al[mt], bh[nt], acc[mt][nt], 0, 0, 0);
                acc[mt][nt] =
                    __builtin_amdgcn_mfma_f32_16x16x32_bf16(ah[mt], bl[nt], acc[mt][nt], 0, 0, 0);
            }

        barrier_lds();  // reads done (lgkmcnt) before next chunk overwrites LDS

        // ---- rotate pipeline regs
        if (ci + 1 < NCH) {
            pA0 = nA0; pA1 = nA1; pA2 = nA2; pA3 = nA3; pA4 = nA4;
            wBh0 = nBh0; wBh1 = nBh1; wBl0 = nBl0; wBl1 = nBl1;
        }
    }

    // ---- epilogue: C/D layout col = lane&15, row = (lane>>4)*4 + reg
    const size_t orow0 = (size_t)b * E_ + e0;
#pragma unroll
    for (int mt = 0; mt < 4; ++mt) {
#pragma unroll
        for (int nt = 0; nt < 4; ++nt) {
            const int col = wn + nt * 16 + l15;
            const size_t r0 = orow0 + wm + mt * 16 + qd * 4;
#pragma unroll
            for (int r = 0; r < 4; ++r) hout[(r0 + r) * 256 + col] = Cvt<TS>::to(acc[mt][nt][r]);
        }
    }
}

// ---------------- out[b][o][e] = leaky(h + h1), fp32, transposed write ----------------
template <typename TS>
__global__ void k_final(const TS* __restrict__ h, const TS* __restrict__ h1,
                        float* __restrict__ out) {
    __shared__ float t[32][33];
    const int b = blockIdx.z, o0 = blockIdx.y * 32, e0 = blockIdx.x * 32;
    const int tx = threadIdx.x & 31, ty = threadIdx.x >> 5;
#pragma unroll
    for (int i = 0; i < 4; ++i) {
        const int e = ty + i * 8;
        const size_t idx = ((size_t)b * E_ + e0 + e) * 256 + o0 + tx;
        t[e][tx] = lk(Cvt<TS>::from(h[idx]) + Cvt<TS>::from(h1[idx]));
    }
    __syncthreads();
#pragma unroll
    for (int i = 0; i < 4; ++i) {
        const int o = ty + i * 8;
        out[((size_t)b * 256 + o0 + o) * E_ + e0 + tx] = t[tx][o];
    }
}

template <typename TS>
static void run_all(const float* x, const int* edges, const float* W0, const float* Ws,
                    const float* gammas, const float* betas, float* out, char* ws,
                    hipStream_t stream) {
    const size_t hbytes = (size_t)B_ * E_ * 256 * sizeof(TS);
    TS* h1 = (TS*)(ws);
    TS* hA = (TS*)(ws + hbytes);
    TS* hB = (TS*)(ws + 2 * hbytes);
    TS* xT = (TS*)(ws + 2 * hbytes);  // alias hB: dead before conv3 writes hB
    char* wp = ws + 3 * hbytes;
    __hip_bfloat16* w0h = (__hip_bfloat16*)(wp);
    __hip_bfloat16* w0l = (__hip_bfloat16*)(wp + 524288);
    __hip_bfloat16* wsh[3], *wsl[3];
    for (int i = 0; i < 3; ++i) {
        wsh[i] = (__hip_bfloat16*)(wp + 1048576 + (size_t)i * 2097152);
        wsl[i] = (__hip_bfloat16*)(wp + 1048576 + (size_t)i * 2097152 + 1048576);
    }
    float* stats = (float*)(wp + 7340032);
    float* scale = (float*)(wp + 7342080);
    float* bias = (float*)(wp + 7343104);

    k_transpose_x<TS><<<dim3(E_ / 32, 4, B_), 256, 0, stream>>>(x, xT);
    k_prep_w<<<128, 256, 0, stream>>>(W0, w0h, w0l, 128);
    for (int i = 0; i < 3; ++i)
        k_prep_w<<<256, 256, 0, stream>>>(Ws + (size_t)i * 458752, wsh[i], wsl[i], 256);

    const dim3 gconv(512);
    k_conv<128, false, TS><<<gconv, 512, 0, stream>>>(xT, edges, w0h, w0l, nullptr, nullptr, h1);

    TS* bin[3] = {h1, hA, hB};
    TS* bout[3] = {hA, hB, hA};
    for (int i = 0; i < 3; ++i) {
        hipMemsetAsync(stats, 0, 512 * sizeof(float), stream);
        k_bn_stats<TS><<<1024, 256, 0, stream>>>(bin[i], stats);
        k_bn_finalize<<<1, 256, 0, stream>>>(stats, gammas + 256 * i, betas + 256 * i, scale, bias);
        k_conv<256, true, TS><<<gconv, 512, 0, stream>>>(bin[i], edges, wsh[i], wsl[i], scale, bias,
                                                         bout[i]);
    }
    k_final<TS><<<dim3(E_ / 32, 256 / 32, B_), 256, 0, stream>>>(hA, h1, out);
}

extern "C" void kernel_launch(void* const* d_in, const int* in_sizes, int n_in, void* d_out,
                              int out_size, void* d_ws, size_t ws_size, hipStream_t stream) {
    const float* x = (const float*)d_in[0];
    const int* edges = (const int*)d_in[1];
    const float* W0 = (const float*)d_in[2];
    const float* Ws = (const float*)d_in[3];
    const float* gammas = (const float*)d_in[4];
    const float* betas = (const float*)d_in[5];
    float* out = (float*)d_out;
    char* ws = (char*)d_ws;

    // fp32-h path needs 3*64MB + ~7.1MB of weights/stats = 208,670,720 B.
    if (ws_size >= 208670720ULL + 4096ULL)
        run_all<float>(x, edges, W0, Ws, gammas, betas, out, ws, stream);
    else
        run_all<__hip_bfloat16>(x, edges, W0, Ws, gammas, betas, out, ws, stream);
}

// Round 5
// 1862.794 us; speedup vs baseline: 1.0028x; 1.0028x over previous
//
#include <hip/hip_runtime.h>
#include <hip/hip_bf16.h>

// MeshConvNet on MI355X (gfx950) — round 5: fix gather/staging throughput.
// r4 postmortem: bottleneck = scattered 4B gathers (64 lines per wave-load) + per-chunk
// overheads, not the barrier drain. This round: role-split 512-thr block (4 gather waves
// w/ float4 loads + line-sharing lane pairs; 4 B-staging waves w/ fused-repacked W),
// 8-channel chunks (32 iters), prefetch 1 chunk ahead, LDS-scoped barriers.
// Numerics unchanged: fp32 h, 3-product split-bf16 MFMA GEMM.

#define B_ 4
#define E_ 16384

typedef short short8 __attribute__((ext_vector_type(8)));
typedef float floatx4 __attribute__((ext_vector_type(4)));

__device__ __forceinline__ float lk(float v) { return v > 0.0f ? v : 0.01f * v; }
__device__ __forceinline__ float b2f(__hip_bfloat16 h) { return __bfloat162float(h); }
__device__ __forceinline__ __hip_bfloat16 f2b(float f) { return __float2bfloat16(f); }

// Barrier that only waits on LDS (lgkmcnt), not in-flight global loads (vmcnt).
__device__ __forceinline__ void barrier_lds() {
    __builtin_amdgcn_fence(__ATOMIC_RELEASE, "workgroup", "local");
    __builtin_amdgcn_s_barrier();
    __builtin_amdgcn_fence(__ATOMIC_ACQUIRE, "workgroup", "local");
}

template <typename TS>
struct Cvt;
template <>
struct Cvt<float> {
    static __device__ __forceinline__ float to(float f) { return f; }
    static __device__ __forceinline__ float from(float s) { return s; }
    static __device__ __forceinline__ void ld4(const float* p, float* o) {
        const float4 v = *reinterpret_cast<const float4*>(p);
        o[0] = v.x; o[1] = v.y; o[2] = v.z; o[3] = v.w;
    }
};
template <>
struct Cvt<__hip_bfloat16> {
    static __device__ __forceinline__ __hip_bfloat16 to(float f) { return f2b(f); }
    static __device__ __forceinline__ float from(__hip_bfloat16 s) { return b2f(s); }
    static __device__ __forceinline__ void ld4(const __hip_bfloat16* p, float* o) {
        union { uint2 u; __hip_bfloat16 h[4]; } v;
        v.u = *reinterpret_cast<const uint2*>(p);
        o[0] = b2f(v.h[0]); o[1] = b2f(v.h[1]); o[2] = b2f(v.h[2]); o[3] = b2f(v.h[3]);
    }
};

// ---------------- x [B][128][E] fp32 -> xT [B*E][128] TS ----------------
template <typename TS>
__global__ void k_transpose_x(const float* __restrict__ x, TS* __restrict__ xT) {
    __shared__ float t[32][33];
    const int b = blockIdx.z, c0 = blockIdx.y * 32, e0 = blockIdx.x * 32;
    const int tx = threadIdx.x & 31, ty = threadIdx.x >> 5;
#pragma unroll
    for (int i = 0; i < 4; ++i) {
        const int c = ty + i * 8;
        t[c][tx] = x[((size_t)b * 128 + c0 + c) * E_ + e0 + tx];
    }
    __syncthreads();
#pragma unroll
    for (int i = 0; i < 4; ++i) {
        const int e = ty + i * 8;
        xT[((size_t)b * E_ + e0 + e) * 128 + c0 + tx] = Cvt<TS>::to(t[tx][e]);
    }
}

// ---- W [256][C][7] fp32 -> fused wf [256][C/8][128] bf16: per chunk [hi 64 | lo 64],
//      k-within-chunk = (c&7)*8 + f, f=7 slot zero. ----
__global__ void k_prep_w(const float* __restrict__ w, __hip_bfloat16* __restrict__ wf, int C) {
    const int idx = blockIdx.x * blockDim.x + threadIdx.x;  // o*C + c
    if (idx >= 256 * C) return;
    const int o = idx / C, c = idx % C;
    const float* src = w + (size_t)idx * 7;
    __hip_bfloat16* dst = wf + ((size_t)o * (C / 8) + (c >> 3)) * 128 + (c & 7) * 8;
#pragma unroll
    for (int f = 0; f < 7; ++f) {
        const float v = src[f];
        const __hip_bfloat16 hi = f2b(v);
        dst[f] = hi;
        dst[64 + f] = f2b(v - b2f(hi));
    }
    dst[7] = f2b(0.0f);
    dst[71] = f2b(0.0f);
}

// ---------------- per-channel sum & sumsq of leaky(h), h [B*E][256] ----------------
template <typename TS>
__global__ void k_bn_stats(const TS* __restrict__ h, float* __restrict__ stats) {
    const int c = threadIdx.x;
    const size_t r0 = (size_t)blockIdx.x * 64;  // 1024 blocks x 64 rows
    float s = 0.0f, q = 0.0f;
    for (int r = 0; r < 64; ++r) {
        const float v = lk(Cvt<TS>::from(h[(r0 + r) * 256 + c]));
        s += v;
        q += v * v;
    }
    atomicAdd(&stats[c], s);
    atomicAdd(&stats[256 + c], q);
}

__global__ void k_bn_finalize(const float* __restrict__ stats, const float* __restrict__ gamma,
                              const float* __restrict__ beta, float* __restrict__ scale,
                              float* __restrict__ bias) {
    const int c = threadIdx.x;
    const float n = 1.0f / 65536.0f;
    const float mean = stats[c] * n;
    const float var = stats[256 + c] * n - mean * mean;
    const float inv = rsqrtf(var + 1e-5f);
    const float s = gamma[c] * inv;
    scale[c] = s;
    bias[c] = beta[c] - mean * s;
}

// ---------------- fused gather + features + split-bf16 MFMA GEMM ----------------
// 512 thr = 8 waves; tile 128 edges x 256 outs; chunk = 8 channels (64 k x {hi,lo}).
// Waves 0-3 gather (thread = edge x 4-ch-half, float4 loads); waves 4-7 stage W.
// LDS row layout (A and B): [hi ks0(32) | hi ks1(32) | lo ks0(32) | lo ks1(32) | pad 8].
template <int C, bool BN, typename TS>
__global__ __launch_bounds__(512, 2) void k_conv(const TS* __restrict__ hin,
                                                 const int* __restrict__ edges,
                                                 const __hip_bfloat16* __restrict__ wf,
                                                 const float* __restrict__ scale,
                                                 const float* __restrict__ bias,
                                                 TS* __restrict__ hout) {
    constexpr int NCH = C / 8;   // chunks
    constexpr int AS = 136;      // 128 + 8 pad shorts -> 272 B row stride
    __shared__ __align__(16) __hip_bfloat16 Asm[128 * AS];
    __shared__ __align__(16) __hip_bfloat16 Bsm[256 * AS];
    __shared__ float ssc[C];
    __shared__ float ssb[C];

    const int tid = threadIdx.x;
    const int tm = blockIdx.x;  // 512 m-tiles (128 per batch)
    const int b = tm >> 7;
    const int e0 = (tm & 127) * 128;
    const int wave = tid >> 6, lane = tid & 63;
    const bool gatherer = (wave < 4);

    if constexpr (BN) {
        if (tid < C) {
            ssc[tid] = scale[tid];
            ssb[tid] = bias[tid];
        }
    }

    // ---- gatherer assignment: tid<256 -> edge = tid>>1, half = tid&1 (4 channels)
    const int e_loc = (tid & 255) >> 1;
    const int half = tid & 1;
    const TS* rp0;
    const TS* rp1;
    const TS* rp2;
    const TS* rp3;
    const TS* rp4;
    {
        const int4 nb =
            *reinterpret_cast<const int4*>(edges + (((size_t)b * E_) + e0 + e_loc) * 4);
        const size_t rb = (size_t)b * E_;
        const int co = half * 4;
        rp0 = hin + (rb + e0 + e_loc) * C + co;
        rp1 = hin + (rb + nb.x) * C + co;
        rp2 = hin + (rb + nb.y) * C + co;
        rp3 = hin + (rb + nb.z) * C + co;
        rp4 = hin + (rb + nb.w) * C + co;
    }

    // ---- B-stager assignment: g = (tid-256) + t*256, t in [0,16):
    //      row = g>>4, granule = g&15; global wf[(row*NCH + ci)*128 + (g&15)*8]
    const int g0 = tid & 255;

    floatx4 acc[4][4];
#pragma unroll
    for (int i = 0; i < 4; ++i)
#pragma unroll
        for (int j = 0; j < 4; ++j) {
            floatx4 z = {0.0f, 0.0f, 0.0f, 0.0f};
            acc[i][j] = z;
        }

    const int wm = (wave & 1) * 64;   // 0 / 64
    const int wn = (wave >> 1 & 3) * 64;  // 0/64/128/192 (waves 4-7 mirror 0-3)
    const int qd = lane >> 4, l15 = lane & 15;

    // ---- preload chunk 0
    float pf[5][4];
    uint4 wb[16];
    if (gatherer) {
        Cvt<TS>::ld4(rp0, pf[0]);
        Cvt<TS>::ld4(rp1, pf[1]);
        Cvt<TS>::ld4(rp2, pf[2]);
        Cvt<TS>::ld4(rp3, pf[3]);
        Cvt<TS>::ld4(rp4, pf[4]);
    } else {
#pragma unroll
        for (int t = 0; t < 16; ++t) {
            const int g = g0 + t * 256;
            wb[t] = *reinterpret_cast<const uint4*>(wf + ((size_t)(g >> 4) * NCH) * 128 +
                                                    (g & 15) * 8);
        }
    }

    if constexpr (BN) barrier_lds();  // ssc/ssb visibility (no vmcnt drain)

#pragma unroll 2
    for (int ci = 0; ci < NCH; ++ci) {
        // ---- phase 1: write LDS from prefetched regs
        if (gatherer) {
#pragma unroll
            for (int cc = 0; cc < 4; ++cc) {
                float f0 = pf[0][cc], f1 = pf[1][cc], f2 = pf[2][cc], f3 = pf[3][cc],
                      f4 = pf[4][cc];
                if constexpr (BN) {
                    const float sA = ssc[ci * 8 + half * 4 + cc];
                    const float bA = ssb[ci * 8 + half * 4 + cc];
                    f0 = lk(f0) * sA + bA;
                    f1 = lk(f1) * sA + bA;
                    f2 = lk(f2) * sA + bA;
                    f3 = lk(f3) * sA + bA;
                    f4 = lk(f4) * sA + bA;
                }
                float gf[8];
                gf[0] = f0;
                gf[1] = f1 + f3;
                gf[2] = f2 + f4;
                gf[3] = fabsf(f1 - f3);
                gf[4] = fabsf(f2 - f4);
                gf[5] = gf[1] + gf[2];
                const float avg = 0.25f * gf[5];
                const float d1 = f1 - avg, d2 = f2 - avg, d3 = f3 - avg, d4 = f4 - avg;
                gf[6] = d1 * d1 + d2 * d2 + d3 * d3 + d4 * d4;
                gf[7] = 0.0f;
                union U {
                    short8 v;
                    __hip_bfloat16 h[8];
                } uh, ul;
#pragma unroll
                for (int f = 0; f < 8; ++f) {
                    const __hip_bfloat16 hi = f2b(gf[f]);
                    uh.h[f] = hi;
                    ul.h[f] = f2b(gf[f] - b2f(hi));
                }
                // hi at [half*32 + cc*8], lo at [64 + half*32 + cc*8]
                *reinterpret_cast<short8*>(&Asm[e_loc * AS + half * 32 + cc * 8]) = uh.v;
                *reinterpret_cast<short8*>(&Asm[e_loc * AS + 64 + half * 32 + cc * 8]) = ul.v;
            }
        } else {
#pragma unroll
            for (int t = 0; t < 16; ++t) {
                const int g = g0 + t * 256;
                *reinterpret_cast<uint4*>(&Bsm[(g >> 4) * AS + (g & 15) * 8]) = wb[t];
            }
        }

        // ---- issue next chunk's loads (consumed next iteration; fly through MFMA)
        if (ci + 1 < NCH) {
            if (gatherer) {
                const int co = (ci + 1) * 8;
                Cvt<TS>::ld4(rp0 + co, pf[0]);
                Cvt<TS>::ld4(rp1 + co, pf[1]);
                Cvt<TS>::ld4(rp2 + co, pf[2]);
                Cvt<TS>::ld4(rp3 + co, pf[3]);
                Cvt<TS>::ld4(rp4 + co, pf[4]);
            } else {
#pragma unroll
                for (int t = 0; t < 16; ++t) {
                    const int g = g0 + t * 256;
                    wb[t] = *reinterpret_cast<const uint4*>(
                        wf + ((size_t)(g >> 4) * NCH + ci + 1) * 128 + (g & 15) * 8);
                }
            }
        }

        barrier_lds();

        // ---- phase 2: MFMA (all 8 waves), 2 k-steps x 4x4 tiles x 3 products
#pragma unroll
        for (int ks = 0; ks < 2; ++ks) {
            short8 ah[4], al[4], bh[4], bl[4];
#pragma unroll
            for (int mt = 0; mt < 4; ++mt) {
                const int r = (wm + mt * 16 + l15) * AS + ks * 32 + qd * 8;
                ah[mt] = *reinterpret_cast<const short8*>(&Asm[r]);
                al[mt] = *reinterpret_cast<const short8*>(&Asm[r + 64]);
            }
#pragma unroll
            for (int nt = 0; nt < 4; ++nt) {
                const int r = (wn + nt * 16 + l15) * AS + ks * 32 + qd * 8;
                bh[nt] = *reinterpret_cast<const short8*>(&Bsm[r]);
                bl[nt] = *reinterpret_cast<const short8*>(&Bsm[r + 64]);
            }
#pragma unroll
            for (int mt = 0; mt < 4; ++mt)
#pragma unroll
                for (int nt = 0; nt < 4; ++nt) {
                    acc[mt][nt] = __builtin_amdgcn_mfma_f32_16x16x32_bf16(ah[mt], bh[nt],
                                                                          acc[mt][nt], 0, 0, 0);
                    acc[mt][nt] = __builtin_amdgcn_mfma_f32_16x16x32_bf16(al[mt], bh[nt],
                                                                          acc[mt][nt], 0, 0, 0);
                    acc[mt][nt] = __builtin_amdgcn_mfma_f32_16x16x32_bf16(ah[mt], bl[nt],
                                                                          acc[mt][nt], 0, 0, 0);
                }
        }

        barrier_lds();
    }

    // ---- epilogue: C/D layout col = lane&15, row = (lane>>4)*4 + reg
    // waves 0-3 and 4-7 cover the same (wm,wn) grid? No: wn uses (wave>>1)&3 which maps
    // waves {0,1,..,7} -> wn {0,0,64,64,128,128,192,192} and wm alternates -> all 8 distinct.
    const size_t orow0 = (size_t)b * E_ + e0;
#pragma unroll
    for (int mt = 0; mt < 4; ++mt) {
#pragma unroll
        for (int nt = 0; nt < 4; ++nt) {
            const int col = wn + nt * 16 + l15;
            const size_t r0 = orow0 + wm + mt * 16 + qd * 4;
#pragma unroll
            for (int r = 0; r < 4; ++r) hout[(r0 + r) * 256 + col] = Cvt<TS>::to(acc[mt][nt][r]);
        }
    }
}

// ---------------- out[b][o][e] = leaky(h + h1), fp32, transposed write ----------------
template <typename TS>
__global__ void k_final(const TS* __restrict__ h, const TS* __restrict__ h1,
                        float* __restrict__ out) {
    __shared__ float t[32][33];
    const int b = blockIdx.z, o0 = blockIdx.y * 32, e0 = blockIdx.x * 32;
    const int tx = threadIdx.x & 31, ty = threadIdx.x >> 5;
#pragma unroll
    for (int i = 0; i < 4; ++i) {
        const int e = ty + i * 8;
        const size_t idx = ((size_t)b * E_ + e0 + e) * 256 + o0 + tx;
        t[e][tx] = lk(Cvt<TS>::from(h[idx]) + Cvt<TS>::from(h1[idx]));
    }
    __syncthreads();
#pragma unroll
    for (int i = 0; i < 4; ++i) {
        const int o = ty + i * 8;
        out[((size_t)b * 256 + o0 + o) * E_ + e0 + tx] = t[tx][o];
    }
}

template <typename TS>
static void run_all(const float* x, const int* edges, const float* W0, const float* Ws,
                    const float* gammas, const float* betas, float* out, char* ws,
                    hipStream_t stream) {
    const size_t hbytes = (size_t)B_ * E_ * 256 * sizeof(TS);
    TS* h1 = (TS*)(ws);
    TS* hA = (TS*)(ws + hbytes);
    TS* hB = (TS*)(ws + 2 * hbytes);
    TS* xT = (TS*)(ws + 2 * hbytes);  // alias hB: dead before conv3 writes hB
    char* wp = ws + 3 * hbytes;
    __hip_bfloat16* wf0 = (__hip_bfloat16*)(wp);                  // 1 MB (C=128)
    __hip_bfloat16* wfs[3];
    for (int i = 0; i < 3; ++i)
        wfs[i] = (__hip_bfloat16*)(wp + (1u << 20) + (size_t)i * (2u << 20));  // 2 MB each
    float* stats = (float*)(wp + (7u << 20));
    float* scale = (float*)(wp + (7u << 20) + 2048);
    float* bias = (float*)(wp + (7u << 20) + 3072);

    k_transpose_x<TS><<<dim3(E_ / 32, 4, B_), 256, 0, stream>>>(x, xT);
    k_prep_w<<<128, 256, 0, stream>>>(W0, wf0, 128);
    for (int i = 0; i < 3; ++i)
        k_prep_w<<<256, 256, 0, stream>>>(Ws + (size_t)i * 458752, wfs[i], 256);

    const dim3 gconv(512);
    k_conv<128, false, TS><<<gconv, 512, 0, stream>>>(xT, edges, wf0, nullptr, nullptr, h1);

    TS* bin[3] = {h1, hA, hB};
    TS* bout[3] = {hA, hB, hA};
    for (int i = 0; i < 3; ++i) {
        hipMemsetAsync(stats, 0, 512 * sizeof(float), stream);
        k_bn_stats<TS><<<1024, 256, 0, stream>>>(bin[i], stats);
        k_bn_finalize<<<1, 256, 0, stream>>>(stats, gammas + 256 * i, betas + 256 * i, scale, bias);
        k_conv<256, true, TS><<<gconv, 512, 0, stream>>>(bin[i], edges, wfs[i], scale, bias,
                                                         bout[i]);
    }
    k_final<TS><<<dim3(E_ / 32, 256 / 32, B_), 256, 0, stream>>>(hA, h1, out);
}

extern "C" void kernel_launch(void* const* d_in, const int* in_sizes, int n_in, void* d_out,
                              int out_size, void* d_ws, size_t ws_size, hipStream_t stream) {
    const float* x = (const float*)d_in[0];
    const int* edges = (const int*)d_in[1];
    const float* W0 = (const float*)d_in[2];
    const float* Ws = (const float*)d_in[3];
    const float* gammas = (const float*)d_in[4];
    const float* betas = (const float*)d_in[5];
    float* out = (float*)d_out;
    char* ws = (char*)d_ws;

    // fp32-h path needs 3*64MB + 7MB weights + stats = ~208.7 MB.
    if (ws_size >= 208670720ULL + 4096ULL)
        run_all<float>(x, edges, W0, Ws, gammas, betas, out, ws, stream);
    else
        run_all<__hip_bfloat16>(x, edges, W0, Ws, gammas, betas, out, ws, stream);
}

// Round 6
// 1342.281 us; speedup vs baseline: 1.3917x; 1.3878x over previous
//
#include <hip/hip_runtime.h>
#include <hip/hip_bf16.h>

// MeshConvNet on MI355X (gfx950) — round 6: kill the K-loop register spills, cut GEMM work.
// r5 postmortem: WRITE_SIZE 65MB->1.1GB = scratch spills (wb[16] x unroll-2 blew the reg
// budget); the float4-gather win was eaten by scratch traffic. This round:
//   (1) no unroll pragma; B-prefetch halved -> no spills (predict WRITE back to ~66MB)
//   (2) 2-product split GEMM: A = hi+lo bf16 (precision lives here), B = single bf16
//       -> 33% less MFMA, half the B traffic. Expected absmax ~5-7 (threshold 19.6).
// Structure otherwise frozen from r5: role-split 512-thr block, float4 gathers,
// 8-channel chunks, LDS-scoped barriers, prefetch-1-chunk.

#define B_ 4
#define E_ 16384

typedef short short8 __attribute__((ext_vector_type(8)));
typedef float floatx4 __attribute__((ext_vector_type(4)));

__device__ __forceinline__ float lk(float v) { return v > 0.0f ? v : 0.01f * v; }
__device__ __forceinline__ float b2f(__hip_bfloat16 h) { return __bfloat162float(h); }
__device__ __forceinline__ __hip_bfloat16 f2b(float f) { return __float2bfloat16(f); }

// Barrier that only waits on LDS (lgkmcnt), not in-flight global loads (vmcnt).
__device__ __forceinline__ void barrier_lds() {
    __builtin_amdgcn_fence(__ATOMIC_RELEASE, "workgroup", "local");
    __builtin_amdgcn_s_barrier();
    __builtin_amdgcn_fence(__ATOMIC_ACQUIRE, "workgroup", "local");
}

template <typename TS>
struct Cvt;
template <>
struct Cvt<float> {
    static __device__ __forceinline__ float to(float f) { return f; }
    static __device__ __forceinline__ float from(float s) { return s; }
    static __device__ __forceinline__ void ld4(const float* p, float* o) {
        const float4 v = *reinterpret_cast<const float4*>(p);
        o[0] = v.x; o[1] = v.y; o[2] = v.z; o[3] = v.w;
    }
};
template <>
struct Cvt<__hip_bfloat16> {
    static __device__ __forceinline__ __hip_bfloat16 to(float f) { return f2b(f); }
    static __device__ __forceinline__ float from(__hip_bfloat16 s) { return b2f(s); }
    static __device__ __forceinline__ void ld4(const __hip_bfloat16* p, float* o) {
        union { uint2 u; __hip_bfloat16 h[4]; } v;
        v.u = *reinterpret_cast<const uint2*>(p);
        o[0] = b2f(v.h[0]); o[1] = b2f(v.h[1]); o[2] = b2f(v.h[2]); o[3] = b2f(v.h[3]);
    }
};

// ---------------- x [B][128][E] fp32 -> xT [B*E][128] TS ----------------
template <typename TS>
__global__ void k_transpose_x(const float* __restrict__ x, TS* __restrict__ xT) {
    __shared__ float t[32][33];
    const int b = blockIdx.z, c0 = blockIdx.y * 32, e0 = blockIdx.x * 32;
    const int tx = threadIdx.x & 31, ty = threadIdx.x >> 5;
#pragma unroll
    for (int i = 0; i < 4; ++i) {
        const int c = ty + i * 8;
        t[c][tx] = x[((size_t)b * 128 + c0 + c) * E_ + e0 + tx];
    }
    __syncthreads();
#pragma unroll
    for (int i = 0; i < 4; ++i) {
        const int e = ty + i * 8;
        xT[((size_t)b * E_ + e0 + e) * 128 + c0 + tx] = Cvt<TS>::to(t[tx][e]);
    }
}

// ---- W [256][C][7] fp32 -> wf [256][C/8][64] bf16 (hi only): k-in-chunk = (c&7)*8+f ----
__global__ void k_prep_w(const float* __restrict__ w, __hip_bfloat16* __restrict__ wf, int C) {
    const int idx = blockIdx.x * blockDim.x + threadIdx.x;  // o*C + c
    if (idx >= 256 * C) return;
    const int o = idx / C, c = idx % C;
    const float* src = w + (size_t)idx * 7;
    __hip_bfloat16* dst = wf + ((size_t)o * (C / 8) + (c >> 3)) * 64 + (c & 7) * 8;
#pragma unroll
    for (int f = 0; f < 7; ++f) dst[f] = f2b(src[f]);
    dst[7] = f2b(0.0f);
}

// ---------------- per-channel sum & sumsq of leaky(h), h [B*E][256] ----------------
template <typename TS>
__global__ void k_bn_stats(const TS* __restrict__ h, float* __restrict__ stats) {
    const int c = threadIdx.x;
    const size_t r0 = (size_t)blockIdx.x * 64;  // 1024 blocks x 64 rows
    float s = 0.0f, q = 0.0f;
    for (int r = 0; r < 64; ++r) {
        const float v = lk(Cvt<TS>::from(h[(r0 + r) * 256 + c]));
        s += v;
        q += v * v;
    }
    atomicAdd(&stats[c], s);
    atomicAdd(&stats[256 + c], q);
}

__global__ void k_bn_finalize(const float* __restrict__ stats, const float* __restrict__ gamma,
                              const float* __restrict__ beta, float* __restrict__ scale,
                              float* __restrict__ bias) {
    const int c = threadIdx.x;
    const float n = 1.0f / 65536.0f;
    const float mean = stats[c] * n;
    const float var = stats[256 + c] * n - mean * mean;
    const float inv = rsqrtf(var + 1e-5f);
    const float s = gamma[c] * inv;
    scale[c] = s;
    bias[c] = beta[c] - mean * s;
}

// ---------------- fused gather + features + 2-product split-bf16 MFMA GEMM ----------------
// 512 thr = 8 waves; tile 128 edges x 256 outs; chunk = 8 channels (64 k; A has hi+lo).
// Waves 0-3 gather (thread = edge x 4-ch-half, float4 loads); waves 4-7 stage W (hi only).
// A row: [hi 64 | lo 64 | pad 8] shorts; B row: [hi 64 | pad 8] shorts.
template <int C, bool BN, typename TS>
__global__ __launch_bounds__(512, 2) void k_conv(const TS* __restrict__ hin,
                                                 const int* __restrict__ edges,
                                                 const __hip_bfloat16* __restrict__ wf,
                                                 const float* __restrict__ scale,
                                                 const float* __restrict__ bias,
                                                 TS* __restrict__ hout) {
    constexpr int NCH = C / 8;  // chunks
    constexpr int ASA = 136;    // A row stride (shorts)
    constexpr int ASB = 72;     // B row stride (shorts)
    __shared__ __align__(16) __hip_bfloat16 Asm[128 * ASA];
    __shared__ __align__(16) __hip_bfloat16 Bsm[256 * ASB];
    __shared__ float ssc[C];
    __shared__ float ssb[C];

    const int tid = threadIdx.x;
    const int tm = blockIdx.x;  // 512 m-tiles (128 per batch)
    const int b = tm >> 7;
    const int e0 = (tm & 127) * 128;
    const int wave = tid >> 6, lane = tid & 63;
    const bool gatherer = (wave < 4);

    if constexpr (BN) {
        if (tid < C) {
            ssc[tid] = scale[tid];
            ssb[tid] = bias[tid];
        }
    }

    // ---- gatherer assignment: tid<256 -> edge = tid>>1, half = tid&1 (4 channels)
    const int e_loc = (tid & 255) >> 1;
    const int half = tid & 1;
    const TS* rp0;
    const TS* rp1;
    const TS* rp2;
    const TS* rp3;
    const TS* rp4;
    {
        const int4 nb =
            *reinterpret_cast<const int4*>(edges + (((size_t)b * E_) + e0 + e_loc) * 4);
        const size_t rb = (size_t)b * E_;
        const int co = half * 4;
        rp0 = hin + (rb + e0 + e_loc) * C + co;
        rp1 = hin + (rb + nb.x) * C + co;
        rp2 = hin + (rb + nb.y) * C + co;
        rp3 = hin + (rb + nb.z) * C + co;
        rp4 = hin + (rb + nb.w) * C + co;
    }

    // ---- B-stager assignment: g = (tid&255) + t*256, t in [0,8):
    //      row = g>>3, granule = g&7; global wf[(row*NCH + ci)*64 + (g&7)*8]
    const int g0 = tid & 255;

    floatx4 acc[4][4];
#pragma unroll
    for (int i = 0; i < 4; ++i)
#pragma unroll
        for (int j = 0; j < 4; ++j) {
            floatx4 z = {0.0f, 0.0f, 0.0f, 0.0f};
            acc[i][j] = z;
        }

    const int wm = (wave & 1) * 64;        // 0 / 64
    const int wn = ((wave >> 1) & 3) * 64; // waves 0..7 -> wn 0,0,64,64,128,128,192,192
    const int qd = lane >> 4, l15 = lane & 15;

    // ---- preload chunk 0
    float pf[5][4];
    uint4 wb[8];
    if (gatherer) {
        Cvt<TS>::ld4(rp0, pf[0]);
        Cvt<TS>::ld4(rp1, pf[1]);
        Cvt<TS>::ld4(rp2, pf[2]);
        Cvt<TS>::ld4(rp3, pf[3]);
        Cvt<TS>::ld4(rp4, pf[4]);
    } else {
#pragma unroll
        for (int t = 0; t < 8; ++t) {
            const int g = g0 + t * 256;
            wb[t] = *reinterpret_cast<const uint4*>(wf + ((size_t)(g >> 3) * NCH) * 64 +
                                                    (g & 7) * 8);
        }
    }

    if constexpr (BN) barrier_lds();  // ssc/ssb visibility (no vmcnt drain)

    for (int ci = 0; ci < NCH; ++ci) {
        // ---- phase 1: write LDS from prefetched regs
        if (gatherer) {
#pragma unroll
            for (int cc = 0; cc < 4; ++cc) {
                float f0 = pf[0][cc], f1 = pf[1][cc], f2 = pf[2][cc], f3 = pf[3][cc],
                      f4 = pf[4][cc];
                if constexpr (BN) {
                    const float sA = ssc[ci * 8 + half * 4 + cc];
                    const float bA = ssb[ci * 8 + half * 4 + cc];
                    f0 = lk(f0) * sA + bA;
                    f1 = lk(f1) * sA + bA;
                    f2 = lk(f2) * sA + bA;
                    f3 = lk(f3) * sA + bA;
                    f4 = lk(f4) * sA + bA;
                }
                float gf[8];
                gf[0] = f0;
                gf[1] = f1 + f3;
                gf[2] = f2 + f4;
                gf[3] = fabsf(f1 - f3);
                gf[4] = fabsf(f2 - f4);
                gf[5] = gf[1] + gf[2];
                const float avg = 0.25f * gf[5];
                const float d1 = f1 - avg, d2 = f2 - avg, d3 = f3 - avg, d4 = f4 - avg;
                gf[6] = d1 * d1 + d2 * d2 + d3 * d3 + d4 * d4;
                gf[7] = 0.0f;
                union U {
                    short8 v;
                    __hip_bfloat16 h[8];
                } uh, ul;
#pragma unroll
                for (int f = 0; f < 8; ++f) {
                    const __hip_bfloat16 hi = f2b(gf[f]);
                    uh.h[f] = hi;
                    ul.h[f] = f2b(gf[f] - b2f(hi));
                }
                *reinterpret_cast<short8*>(&Asm[e_loc * ASA + half * 32 + cc * 8]) = uh.v;
                *reinterpret_cast<short8*>(&Asm[e_loc * ASA + 64 + half * 32 + cc * 8]) = ul.v;
            }
        } else {
#pragma unroll
            for (int t = 0; t < 8; ++t) {
                const int g = g0 + t * 256;
                *reinterpret_cast<uint4*>(&Bsm[(g >> 3) * ASB + (g & 7) * 8]) = wb[t];
            }
        }

        // ---- issue next chunk's loads (consumed next iteration; fly through MFMA)
        if (ci + 1 < NCH) {
            if (gatherer) {
                const int co = (ci + 1) * 8;
                Cvt<TS>::ld4(rp0 + co, pf[0]);
                Cvt<TS>::ld4(rp1 + co, pf[1]);
                Cvt<TS>::ld4(rp2 + co, pf[2]);
                Cvt<TS>::ld4(rp3 + co, pf[3]);
                Cvt<TS>::ld4(rp4 + co, pf[4]);
            } else {
#pragma unroll
                for (int t = 0; t < 8; ++t) {
                    const int g = g0 + t * 256;
                    wb[t] = *reinterpret_cast<const uint4*>(
                        wf + ((size_t)(g >> 3) * NCH + ci + 1) * 64 + (g & 7) * 8);
                }
            }
        }

        barrier_lds();

        // ---- phase 2: MFMA (all 8 waves), 2 k-steps x 4x4 tiles x 2 products
#pragma unroll
        for (int ks = 0; ks < 2; ++ks) {
            short8 ah[4], al[4], bh[4];
#pragma unroll
            for (int mt = 0; mt < 4; ++mt) {
                const int r = (wm + mt * 16 + l15) * ASA + ks * 32 + qd * 8;
                ah[mt] = *reinterpret_cast<const short8*>(&Asm[r]);
                al[mt] = *reinterpret_cast<const short8*>(&Asm[r + 64]);
            }
#pragma unroll
            for (int nt = 0; nt < 4; ++nt) {
                const int r = (wn + nt * 16 + l15) * ASB + ks * 32 + qd * 8;
                bh[nt] = *reinterpret_cast<const short8*>(&Bsm[r]);
            }
#pragma unroll
            for (int mt = 0; mt < 4; ++mt)
#pragma unroll
                for (int nt = 0; nt < 4; ++nt) {
                    acc[mt][nt] = __builtin_amdgcn_mfma_f32_16x16x32_bf16(ah[mt], bh[nt],
                                                                          acc[mt][nt], 0, 0, 0);
                    acc[mt][nt] = __builtin_amdgcn_mfma_f32_16x16x32_bf16(al[mt], bh[nt],
                                                                          acc[mt][nt], 0, 0, 0);
                }
        }

        barrier_lds();
    }

    // ---- epilogue: C/D layout col = lane&15, row = (lane>>4)*4 + reg
    const size_t orow0 = (size_t)b * E_ + e0;
#pragma unroll
    for (int mt = 0; mt < 4; ++mt) {
#pragma unroll
        for (int nt = 0; nt < 4; ++nt) {
            const int col = wn + nt * 16 + l15;
            const size_t r0 = orow0 + wm + mt * 16 + qd * 4;
#pragma unroll
            for (int r = 0; r < 4; ++r) hout[(r0 + r) * 256 + col] = Cvt<TS>::to(acc[mt][nt][r]);
        }
    }
}

// ---------------- out[b][o][e] = leaky(h + h1), fp32, transposed write ----------------
template <typename TS>
__global__ void k_final(const TS* __restrict__ h, const TS* __restrict__ h1,
                        float* __restrict__ out) {
    __shared__ float t[32][33];
    const int b = blockIdx.z, o0 = blockIdx.y * 32, e0 = blockIdx.x * 32;
    const int tx = threadIdx.x & 31, ty = threadIdx.x >> 5;
#pragma unroll
    for (int i = 0; i < 4; ++i) {
        const int e = ty + i * 8;
        const size_t idx = ((size_t)b * E_ + e0 + e) * 256 + o0 + tx;
        t[e][tx] = lk(Cvt<TS>::from(h[idx]) + Cvt<TS>::from(h1[idx]));
    }
    __syncthreads();
#pragma unroll
    for (int i = 0; i < 4; ++i) {
        const int o = ty + i * 8;
        out[((size_t)b * 256 + o0 + o) * E_ + e0 + tx] = t[tx][o];
    }
}

template <typename TS>
static void run_all(const float* x, const int* edges, const float* W0, const float* Ws,
                    const float* gammas, const float* betas, float* out, char* ws,
                    hipStream_t stream) {
    const size_t hbytes = (size_t)B_ * E_ * 256 * sizeof(TS);
    TS* h1 = (TS*)(ws);
    TS* hA = (TS*)(ws + hbytes);
    TS* hB = (TS*)(ws + 2 * hbytes);
    TS* xT = (TS*)(ws + 2 * hbytes);  // alias hB: dead before conv3 writes hB
    char* wp = ws + 3 * hbytes;
    __hip_bfloat16* wf0 = (__hip_bfloat16*)(wp);  // 512 KB (C=128, hi only)
    __hip_bfloat16* wfs[3];
    for (int i = 0; i < 3; ++i)
        wfs[i] = (__hip_bfloat16*)(wp + (512u << 10) + (size_t)i * (1u << 20));  // 1 MB each
    float* stats = (float*)(wp + (4u << 20));
    float* scale = (float*)(wp + (4u << 20) + 2048);
    float* bias = (float*)(wp + (4u << 20) + 3072);

    k_transpose_x<TS><<<dim3(E_ / 32, 4, B_), 256, 0, stream>>>(x, xT);
    k_prep_w<<<128, 256, 0, stream>>>(W0, wf0, 128);
    for (int i = 0; i < 3; ++i)
        k_prep_w<<<256, 256, 0, stream>>>(Ws + (size_t)i * 458752, wfs[i], 256);

    const dim3 gconv(512);
    k_conv<128, false, TS><<<gconv, 512, 0, stream>>>(xT, edges, wf0, nullptr, nullptr, h1);

    TS* bin[3] = {h1, hA, hB};
    TS* bout[3] = {hA, hB, hA};
    for (int i = 0; i < 3; ++i) {
        hipMemsetAsync(stats, 0, 512 * sizeof(float), stream);
        k_bn_stats<TS><<<1024, 256, 0, stream>>>(bin[i], stats);
        k_bn_finalize<<<1, 256, 0, stream>>>(stats, gammas + 256 * i, betas + 256 * i, scale, bias);
        k_conv<256, true, TS><<<gconv, 512, 0, stream>>>(bin[i], edges, wfs[i], scale, bias,
                                                         bout[i]);
    }
    k_final<TS><<<dim3(E_ / 32, 256 / 32, B_), 256, 0, stream>>>(hA, h1, out);
}

extern "C" void kernel_launch(void* const* d_in, const int* in_sizes, int n_in, void* d_out,
                              int out_size, void* d_ws, size_t ws_size, hipStream_t stream) {
    const float* x = (const float*)d_in[0];
    const int* edges = (const int*)d_in[1];
    const float* W0 = (const float*)d_in[2];
    const float* Ws = (const float*)d_in[3];
    const float* gammas = (const float*)d_in[4];
    const float* betas = (const float*)d_in[5];
    float* out = (float*)d_out;
    char* ws = (char*)d_ws;

    // fp32-h path needs 3*64MB + ~4.1MB weights/stats; keep the established threshold.
    if (ws_size >= 208670720ULL + 4096ULL)
        run_all<float>(x, edges, W0, Ws, gammas, betas, out, ws, stream);
    else
        run_all<__hip_bfloat16>(x, edges, W0, Ws, gammas, betas, out, ws, stream);
}